// Round 2
// baseline (105.726 us; speedup 1.0000x reference)
//
#include <hip/hip_runtime.h>

// Problem constants
#define SRC    16384      // 128*128 source pixels
#define DCH    64         // channels
#define NCLS   19         // classes
#define NPAIR  (NCLS*DCH) // 1216 (c,d) pairs
#define SLICES 4          // pixel slices per pair (tail-quantization fix)

// GUARANTEED bare v_exp_f32 via inline asm. Args are always <= 0 here;
// flush-to-zero on underflow matches the reference's f32 exp behavior.
__device__ __forceinline__ float exp2_raw(float x)
{
    float r;
    asm("v_exp_f32 %0, %1" : "=v"(r) : "v"(x));
    return r;
}

// ---------------------------------------------------------------------------
// K0: zero the per-class allocation counters (workspace is harness-poisoned,
// and K1's atomic base allocation needs them to start at 0).
// ---------------------------------------------------------------------------
__global__ __launch_bounds__(64) void hl_zero_kernel(unsigned int* __restrict__ nnz)
{
    if (threadIdx.x < NCLS) nnz[threadIdx.x] = 0u;
}

// ---------------------------------------------------------------------------
// K1: per-source-pixel class counts + per-class compaction.
// Each source pixel covers a 4x4 block of the 512x512 label map.
// For each class c, pixels with count>0 are compacted into
// entries[c*SRC + slot] = pixel_idx | (count<<14)  (count<=16 fits 5 bits).
// Slot allocation: per-wave ballot rank + block scan + one atomicAdd per
// (class, block) on nnz[c]. Order across blocks is nondeterministic (atomic
// bases) but within-block it is pixel-ordered -> near-sorted lists -> good
// gather locality downstream. ~58% of pixels survive per class.
// ---------------------------------------------------------------------------
__global__ __launch_bounds__(256) void hl_count_compact(
    const int* __restrict__ label, unsigned int* __restrict__ entries,
    unsigned int* __restrict__ nnz)
{
    int t = threadIdx.x;
    int s = blockIdx.x * 256 + t;       // 64 blocks x 256 = 16384
    int sy = s >> 7, sx = s & 127;
    const int4* lab4 = (const int4*)label;
    int l[16];
#pragma unroll
    for (int r = 0; r < 4; r++) {
        int4 v = lab4[(4 * sy + r) * 128 + sx];
        l[4 * r + 0] = v.x; l[4 * r + 1] = v.y;
        l[4 * r + 2] = v.z; l[4 * r + 3] = v.w;
    }
    int cc[NCLS];
#pragma unroll
    for (int c = 0; c < NCLS; c++) {
        int n = 0;
#pragma unroll
        for (int j = 0; j < 16; j++) n += (l[j] == c) ? 1 : 0;
        cc[c] = n;
    }

    __shared__ int wcnt[NCLS][4];
    __shared__ int sbase[NCLS][4];
    int lane = t & 63, wid = t >> 6;
    unsigned long long lt = (1ULL << lane) - 1ULL;

#pragma unroll
    for (int c = 0; c < NCLS; c++) {
        unsigned long long m = __ballot(cc[c] > 0);
        if (lane == 0) wcnt[c][wid] = __popcll(m);
    }
    __syncthreads();
    if (t < NCLS) {
        int a0 = wcnt[t][0], a1 = wcnt[t][1], a2 = wcnt[t][2], a3 = wcnt[t][3];
        unsigned int base = atomicAdd(&nnz[t], (unsigned int)(a0 + a1 + a2 + a3));
        sbase[t][0] = (int)base;
        sbase[t][1] = (int)base + a0;
        sbase[t][2] = (int)base + a0 + a1;
        sbase[t][3] = (int)base + a0 + a1 + a2;
    }
    __syncthreads();
#pragma unroll
    for (int c = 0; c < NCLS; c++) {
        unsigned long long m = __ballot(cc[c] > 0);
        int rank = __popcll(m & lt);
        if (cc[c] > 0)
            entries[c * SRC + sbase[c][wid] + rank] =
                (unsigned int)s | ((unsigned int)cc[c] << 14);
    }
}

// ---------------------------------------------------------------------------
// K2a: moments over compacted entries. Grid = NPAIR*SLICES; block (pair,slice)
// reduces its slice to f64 partials written to DISJOINT slots (no atomics,
// no zero-init). K2b combines the 4 slices on thread 0.
// ---------------------------------------------------------------------------
__global__ __launch_bounds__(256, 4) void hl_moments(
    const float* __restrict__ feature, const unsigned int* __restrict__ entries,
    const unsigned int* __restrict__ nnz,
    double* __restrict__ ms1, double* __restrict__ ms2,
    unsigned int* __restrict__ mn)
{
    int bx = blockIdx.x;
    int pair = bx >> 2, slice = bx & 3;
    int c = pair >> 6, d = pair & 63;
    int t = threadIdx.x;

    int nz  = (int)nnz[c];
    int per = (nz + SLICES - 1) >> 2;
    int jb  = slice * per;
    int j1  = min(jb + per, nz);
    const unsigned int* lst = entries + c * SRC;
    const float*        fd  = feature + d * SRC;

    float f1 = 0.f, f2 = 0.f;
    unsigned int ncnt = 0;
    for (int j = jb + t; j < j1; j += 256) {
        unsigned int e  = lst[j];
        float        x  = fd[e & 16383u];
        unsigned int cu = e >> 14;
        float        cf = (float)cu;
        float        wx = cf * x;
        f1 += wx;
        f2 = fmaf(wx, x, f2);
        ncnt += cu;
    }
    double s1 = (double)f1, s2 = (double)f2;
#pragma unroll
    for (int o = 32; o > 0; o >>= 1) {
        s1 += __shfl_down(s1, o);
        s2 += __shfl_down(s2, o);
        ncnt += __shfl_down(ncnt, o);
    }
    __shared__ double       p1[4], p2[4];
    __shared__ unsigned int pn[4];
    int wid = t >> 6;
    if ((t & 63) == 0) { p1[wid] = s1; p2[wid] = s2; pn[wid] = ncnt; }
    __syncthreads();
    if (t == 0) {
        int idx = pair * SLICES + slice;
        ms1[idx] = p1[0] + p1[1] + p1[2] + p1[3];
        ms2[idx] = p2[0] + p2[1] + p2[2] + p2[3];
        mn[idx]  = pn[0] + pn[1] + pn[2] + pn[3];
    }
}

// ---------------------------------------------------------------------------
// K2b: KDE over compacted entries. Grid = NPAIR*SLICES (4864 blocks -> tail
// quantization ~1.2x instead of 1216/1024 = 1.8x). Thread 0 combines the 4
// moment slices -> mu, istd, active. 7-bin KDE with k^2-CSE (k^2 in {0,1,4,9}
// -> 3 adds, and exp2(q) directly for k=0). Per-slice bin partials written
// to disjoint slots (no atomics); K4 combines.
// ---------------------------------------------------------------------------
__global__ __launch_bounds__(256, 4) void hl_kde(
    const float* __restrict__ feature, const unsigned int* __restrict__ entries,
    const unsigned int* __restrict__ nnz,
    const double* __restrict__ ms1, const double* __restrict__ ms2,
    const unsigned int* __restrict__ mn, float* __restrict__ bins)
{
    int bx = blockIdx.x;
    int pair = bx >> 2, slice = bx & 3;
    int c = pair >> 6, d = pair & 63;
    int t = threadIdx.x;

    __shared__ float sh_istd, sh_nm;
    __shared__ int   sh_act;
    if (t == 0) {
        int base = pair * SLICES;
        unsigned int n = mn[base] + mn[base + 1] + mn[base + 2] + mn[base + 3];
        double a = ms1[base] + ms1[base + 1] + ms1[base + 2] + ms1[base + 3];
        double b = ms2[base] + ms2[base + 1] + ms2[base + 2] + ms2[base + 3];
        double nsafe = (n > 0) ? (double)n : 1.0;
        double mu  = a / nsafe;
        double var = (b - 2.0 * mu * a + mu * mu * (double)n) / nsafe + 1e-10;
        float istd = (float)(1.0 / sqrt(var));
        sh_istd = istd;
        sh_nm   = -(float)mu * istd;    // u = fma(x, istd, nm)
        sh_act  = (n >= 1000);
    }
    __syncthreads();
    if (!sh_act) return;                // inactive class: K4 skips its bins
    float istd = sh_istd, nm = sh_nm;

    int nz  = (int)nnz[c];
    int per = (nz + SLICES - 1) >> 2;
    int jb  = slice * per;
    int j1  = min(jb + per, nz);
    const unsigned int* lst = entries + c * SRC;
    const float*        fd  = feature + d * SRC;

    const float C1 = -18.033688011112042f;   // -12.5 * log2(e)
    float acc[7] = {0.f, 0.f, 0.f, 0.f, 0.f, 0.f, 0.f};

#pragma unroll 2
    for (int j = jb + t; j < j1; j += 256) {
        unsigned int e = lst[j];
        float x  = fd[e & 16383u];
        float cf = (float)(e >> 14);
        float u  = fmaf(x, istd, nm);
        float p  = C1 * u;
        float q  = p * u;                    // C1*u^2
        float t1 = q + C1;                   // + C1*1
        float t4 = q + 4.f * C1;             // + C1*4
        float t9 = q + 9.f * C1;             // + C1*9
        acc[0] = fmaf(cf, exp2_raw(fmaf(p,  6.f, t9)), acc[0]);  // k=-3
        acc[1] = fmaf(cf, exp2_raw(fmaf(p,  4.f, t4)), acc[1]);  // k=-2
        acc[2] = fmaf(cf, exp2_raw(fmaf(p,  2.f, t1)), acc[2]);  // k=-1
        acc[3] = fmaf(cf, exp2_raw(q),                 acc[3]);  // k= 0
        acc[4] = fmaf(cf, exp2_raw(fmaf(p, -2.f, t1)), acc[4]);  // k=+1
        acc[5] = fmaf(cf, exp2_raw(fmaf(p, -4.f, t4)), acc[5]);  // k=+2
        acc[6] = fmaf(cf, exp2_raw(fmaf(p, -6.f, t9)), acc[6]);  // k=+3
    }

    __shared__ float part[4][7];
    int wid = t >> 6;
#pragma unroll
    for (int j = 0; j < 7; j++) {
        float v = acc[j];
#pragma unroll
        for (int o = 32; o > 0; o >>= 1) v += __shfl_down(v, o);
        if ((t & 63) == 0) part[wid][j] = v;
    }
    __syncthreads();
    if (t < 7)
        bins[(pair * SLICES + slice) * 7 + t] =
            part[0][t] + part[1][t] + part[2][t] + part[3][t];
}

// ---------------------------------------------------------------------------
// K4: finalize. One block: per pair combine 4 bin slices, normalize, smooth-L1
// vs fixed target, sum over active pairs, divide by 448*A. Writes out
// absolutely (poisoned d_out needs no pre-zero). Replaces psum atomics + K3.
// ---------------------------------------------------------------------------
__global__ __launch_bounds__(256) void hl_final_kernel(
    const float* __restrict__ bins, const unsigned int* __restrict__ mn,
    float* __restrict__ out)
{
    int t = threadIdx.x;
    // target: exp(-0.5 k^2)/Z (1/sqrt(2 pi var) cancels in normalization)
    double e[7], z = 0.0;
#pragma unroll
    for (int k = -3; k <= 3; k++) { e[k + 3] = exp(-0.5 * (double)(k * k)); z += e[k + 3]; }
    float tg[7];
#pragma unroll
    for (int j = 0; j < 7; j++) tg[j] = (float)(e[j] / z);

    float tot = 0.f;
    for (int pair = t; pair < NPAIR; pair += 256) {
        int c  = pair >> 6;
        int nb = (c << 6) * SLICES;     // class-c pair with d=0
        unsigned int n = mn[nb] + mn[nb + 1] + mn[nb + 2] + mn[nb + 3];
        if (n < 1000) continue;         // inactive: contributes 0
        float h[7], S = 0.f;
#pragma unroll
        for (int j = 0; j < 7; j++) {
            int bb = pair * (SLICES * 7) + j;
            h[j] = bins[bb] + bins[bb + 7] + bins[bb + 14] + bins[bb + 21];
            S += h[j];
        }
        float Ss = fmaxf(S, 1e-30f);
        float ps = 0.f;
#pragma unroll
        for (int j = 0; j < 7; j++) {
            float dd = fabsf(h[j] / Ss - tg[j]);
            ps += (dd < 1.f) ? 0.5f * dd * dd : (dd - 0.5f);
        }
        tot += ps;
    }
#pragma unroll
    for (int o = 32; o > 0; o >>= 1) tot += __shfl_down(tot, o);
    __shared__ float pr[4];
    int wid = t >> 6;
    if ((t & 63) == 0) pr[wid] = tot;
    __syncthreads();
    if (t == 0) {
        float T = pr[0] + pr[1] + pr[2] + pr[3];
        int A = 0;
#pragma unroll
        for (int c = 0; c < NCLS; c++) {
            int nb = (c << 6) * SLICES;
            unsigned int n = mn[nb] + mn[nb + 1] + mn[nb + 2] + mn[nb + 3];
            A += (n >= 1000) ? 1 : 0;
        }
        out[0] = (A > 0) ? T / (448.0f * (float)A) : 0.0f;
    }
}

// ---------------------------------------------------------------------------
// Workspace layout (256-aligned):
//   entries : NCLS*SRC*4              = 1,245,184 B  @ 0
//   ms1     : NPAIR*SLICES*8          =    38,912 B  @ 1,245,184
//   ms2     : NPAIR*SLICES*8          =    38,912 B  @ 1,284,096
//   mn      : NPAIR*SLICES*4          =    19,456 B  @ 1,323,008
//   bins    : NPAIR*SLICES*7*4        =   136,192 B  @ 1,342,464
//   nnz     : NCLS*4 (pad 128)        =       128 B  @ 1,478,656
// ---------------------------------------------------------------------------
extern "C" void kernel_launch(void* const* d_in, const int* in_sizes, int n_in,
                              void* d_out, int out_size, void* d_ws, size_t ws_size,
                              hipStream_t stream)
{
    const float* feature = (const float*)d_in[0];   // [1,64,128,128] fp32
    const int*   label   = (const int*)d_in[1];     // [1,1,512,512]  int32
    float*       out     = (float*)d_out;           // scalar fp32

    char* ws = (char*)d_ws;
    unsigned int* entries = (unsigned int*)(ws);
    double*       ms1     = (double*)(ws + 1245184);
    double*       ms2     = (double*)(ws + 1284096);
    unsigned int* mn      = (unsigned int*)(ws + 1323008);
    float*        bins    = (float*)(ws + 1342464);
    unsigned int* nnz     = (unsigned int*)(ws + 1478656);

    hl_zero_kernel<<<1, 64, 0, stream>>>(nnz);
    hl_count_compact<<<SRC / 256, 256, 0, stream>>>(label, entries, nnz);
    hl_moments<<<NPAIR * SLICES, 256, 0, stream>>>(feature, entries, nnz, ms1, ms2, mn);
    hl_kde<<<NPAIR * SLICES, 256, 0, stream>>>(feature, entries, nnz, ms1, ms2, mn, bins);
    hl_final_kernel<<<1, 256, 0, stream>>>(bins, mn, out);
}

// Round 3
// 102.823 us; speedup vs baseline: 1.0282x; 1.0282x over previous
//
#include <hip/hip_runtime.h>

// Problem constants
#define SRC    16384      // 128*128 source pixels
#define DCH    64         // channels
#define NCLS   19         // classes
#define NPAIR  (NCLS*DCH) // 1216 (c,d) pairs
#define KSL    4          // KDE slices per pair (tail-quantization fix)

// GUARANTEED bare v_exp_f32 via inline asm. Args here are <= 0;
// flush-to-zero on underflow matches the reference's f32 exp behavior.
__device__ __forceinline__ float exp2_raw(float x)
{
    float r;
    asm("v_exp_f32 %0, %1" : "=v"(r) : "v"(x));
    return r;
}

// ---------------------------------------------------------------------------
// K1: per-source-pixel class counts (proven baseline body, psum removed).
// Each source pixel covers a 4x4 block of the 512x512 label map.
// cnt[c*SRC + s] = #subpixels with label c (0..16).
// ---------------------------------------------------------------------------
__global__ __launch_bounds__(256) void hl_count_kernel(
    const int* __restrict__ label, unsigned char* __restrict__ cnt)
{
    int s  = blockIdx.x * 256 + threadIdx.x;   // 64 blocks x 256 = 16384
    int sy = s >> 7, sx = s & 127;
    const int4* lab4 = (const int4*)label;
    int l[16];
#pragma unroll
    for (int r = 0; r < 4; r++) {
        int4 v = lab4[(4 * sy + r) * 128 + sx];
        l[4 * r + 0] = v.x; l[4 * r + 1] = v.y;
        l[4 * r + 2] = v.z; l[4 * r + 3] = v.w;
    }
#pragma unroll
    for (int c = 0; c < NCLS; c++) {
        int cc = 0;
#pragma unroll
        for (int j = 0; j < 16; j++) cc += (l[j] == c) ? 1 : 0;
        cnt[c * SRC + s] = (unsigned char)cc;
    }
}

// ---------------------------------------------------------------------------
// K2a: moments per (c,d) pair. Identical pass-1 body to the proven fused
// kernel (float4 feature + packed-cnt uint, f32 partials -> f64 reduce).
// Thread 0 writes minfo[pair] = {istd, nm, act, 0} and (d==0) ncls[c] = n.
// Unit time ~1/4 of the old fused block, so the 1216-block 2-batch tail
// costs ~1/4 of what it did fused.
// ---------------------------------------------------------------------------
__global__ __launch_bounds__(256, 4) void hl_moments(
    const float* __restrict__ feature, const unsigned char* __restrict__ cnt,
    float4* __restrict__ minfo, unsigned int* __restrict__ ncls)
{
    int w = blockIdx.x;             // pair 0..1215
    int c = w >> 6, d = w & 63;
    int t = threadIdx.x;
    int wid = t >> 6;

    const float4*       fp4 = (const float4*)(feature + d * SRC);
    const unsigned int* cpu = (const unsigned int*)(cnt + c * SRC);

    float f1 = 0.f, f2 = 0.f;
    int   nc = 0;
#pragma unroll 4
    for (int i = 0; i < 16; i++) {
        int g = i * 256 + t;        // 4096 float4-groups (= 4096 uint groups)
        float4       x  = fp4[g];
        unsigned int cv = cpu[g];
        float xs[4] = {x.x, x.y, x.z, x.w};
        float cf[4] = {(float)(cv & 255u), (float)((cv >> 8) & 255u),
                       (float)((cv >> 16) & 255u), (float)(cv >> 24)};
#pragma unroll
        for (int e = 0; e < 4; e++) {
            float wx = cf[e] * xs[e];
            f1 += wx;
            f2 = fmaf(wx, xs[e], f2);
        }
        nc += (cv & 255u) + ((cv >> 8) & 255u) + ((cv >> 16) & 255u) + (cv >> 24);
    }
    double s1 = (double)f1, s2 = (double)f2;
#pragma unroll
    for (int o = 32; o > 0; o >>= 1) {
        s1 += __shfl_down(s1, o);
        s2 += __shfl_down(s2, o);
        nc += __shfl_down(nc, o);
    }
    __shared__ double ps1[4], ps2[4];
    __shared__ int    pn[4];
    if ((t & 63) == 0) { ps1[wid] = s1; ps2[wid] = s2; pn[wid] = nc; }
    __syncthreads();
    if (t == 0) {
        double a = ps1[0] + ps1[1] + ps1[2] + ps1[3];
        double b = ps2[0] + ps2[1] + ps2[2] + ps2[3];
        int    n = pn[0] + pn[1] + pn[2] + pn[3];
        double nsafe = (n > 0) ? (double)n : 1.0;
        double mu  = a / nsafe;
        double var = (b - 2.0 * mu * a + mu * mu * (double)n) / nsafe + 1e-10;
        float istd = (float)(1.0 / sqrt(var));
        float muf  = (float)mu;
        float4 mi;
        mi.x = istd;
        mi.y = -muf * istd;                 // u = fma(x, istd, nm)
        mi.z = (n >= 1000) ? 1.0f : 0.0f;   // act
        mi.w = 0.f;
        minfo[w] = mi;
        if (d == 0) ncls[c] = (unsigned int)n;  // same-stream next-kernel read
    }
}

// ---------------------------------------------------------------------------
// K2b: KDE. Grid = NPAIR*KSL = 4864 blocks -> makespan ~1.25x ideal instead
// of the fused kernel's ~2x (1216 blocks on a 1024-block-resident machine).
// Exact proven inner loop (float4 + packed cnt, 0.5 VMEM-instr/element) with
// k^2-CSE (k^2 in {0,1,4,9} -> 3 adds; exp2(q) directly for k=0).
// mu/istd/act come from one broadcast float4 load; no serial section.
// Per-slice bin partials go to disjoint slots (no atomics); K4 combines.
// ---------------------------------------------------------------------------
__global__ __launch_bounds__(256, 4) void hl_kde(
    const float* __restrict__ feature, const unsigned char* __restrict__ cnt,
    const float4* __restrict__ minfo, float* __restrict__ bins)
{
    int bx = blockIdx.x;
    int pair = bx >> 2, slice = bx & 3;
    int c = pair >> 6, d = pair & 63;
    int t = threadIdx.x;

    float4 mi = minfo[pair];
    if (mi.z == 0.0f) return;       // inactive class: K4 skips its bins
    float istd = mi.x, nm = mi.y;

    const float4*       fp4 = (const float4*)(feature + d * SRC);
    const unsigned int* cpu = (const unsigned int*)(cnt + c * SRC);

    const float C1 = -18.033688011112042f;   // -12.5 * log2(e)
    float acc[7] = {0.f, 0.f, 0.f, 0.f, 0.f, 0.f, 0.f};

#pragma unroll
    for (int i = 0; i < 4; i++) {
        int g = slice * 1024 + i * 256 + t;  // quarter of the 4096 groups
        float4       x  = fp4[g];
        unsigned int cv = cpu[g];
        float xs[4] = {x.x, x.y, x.z, x.w};
        float cf[4] = {(float)(cv & 255u), (float)((cv >> 8) & 255u),
                       (float)((cv >> 16) & 255u), (float)(cv >> 24)};
#pragma unroll
        for (int e = 0; e < 4; e++) {
            float u  = fmaf(xs[e], istd, nm);
            float p  = C1 * u;
            float q  = p * u;                // C1*u^2
            float t1 = q + C1;               // + C1*1
            float t4 = q + 4.f * C1;         // + C1*4
            float t9 = q + 9.f * C1;         // + C1*9
            acc[0] = fmaf(cf[e], exp2_raw(fmaf(p,  6.f, t9)), acc[0]); // k=-3
            acc[1] = fmaf(cf[e], exp2_raw(fmaf(p,  4.f, t4)), acc[1]); // k=-2
            acc[2] = fmaf(cf[e], exp2_raw(fmaf(p,  2.f, t1)), acc[2]); // k=-1
            acc[3] = fmaf(cf[e], exp2_raw(q),                 acc[3]); // k= 0
            acc[4] = fmaf(cf[e], exp2_raw(fmaf(p, -2.f, t1)), acc[4]); // k=+1
            acc[5] = fmaf(cf[e], exp2_raw(fmaf(p, -4.f, t4)), acc[5]); // k=+2
            acc[6] = fmaf(cf[e], exp2_raw(fmaf(p, -6.f, t9)), acc[6]); // k=+3
        }
    }

    __shared__ float part[4][7];
    int wid = t >> 6;
#pragma unroll
    for (int j = 0; j < 7; j++) {
        float v = acc[j];
#pragma unroll
        for (int o = 32; o > 0; o >>= 1) v += __shfl_down(v, o);
        if ((t & 63) == 0) part[wid][j] = v;
    }
    __syncthreads();
    if (t < 7)
        bins[bx * 7 + t] = part[0][t] + part[1][t] + part[2][t] + part[3][t];
}

// ---------------------------------------------------------------------------
// K4: finalize. One block: per pair combine 4 bin slices, normalize, smooth-L1
// vs fixed target, sum over active pairs, divide by 448*A. Writes out
// absolutely (poisoned d_out needs no pre-zero). No atomics anywhere.
// ---------------------------------------------------------------------------
__global__ __launch_bounds__(256) void hl_final_kernel(
    const float* __restrict__ bins, const unsigned int* __restrict__ ncls,
    float* __restrict__ out)
{
    int t = threadIdx.x;
    // target: exp(-0.5 k^2)/Z (1/sqrt(2 pi var) cancels in normalization)
    double e[7], z = 0.0;
#pragma unroll
    for (int k = -3; k <= 3; k++) { e[k + 3] = exp(-0.5 * (double)(k * k)); z += e[k + 3]; }
    float tg[7];
#pragma unroll
    for (int j = 0; j < 7; j++) tg[j] = (float)(e[j] / z);

    float tot = 0.f;
    for (int pair = t; pair < NPAIR; pair += 256) {
        int c = pair >> 6;
        if (ncls[c] < 1000u) continue;  // inactive: contributes 0 (bins unwritten)
        float h[7], S = 0.f;
#pragma unroll
        for (int j = 0; j < 7; j++) {
            int bb = pair * (KSL * 7) + j;
            h[j] = bins[bb] + bins[bb + 7] + bins[bb + 14] + bins[bb + 21];
            S += h[j];
        }
        float Ss = fmaxf(S, 1e-30f);
        float ps = 0.f;
#pragma unroll
        for (int j = 0; j < 7; j++) {
            float dd = fabsf(h[j] / Ss - tg[j]);
            ps += (dd < 1.f) ? 0.5f * dd * dd : (dd - 0.5f);
        }
        tot += ps;
    }
#pragma unroll
    for (int o = 32; o > 0; o >>= 1) tot += __shfl_down(tot, o);
    __shared__ float pr[4];
    int wid = t >> 6;
    if ((t & 63) == 0) pr[wid] = tot;
    __syncthreads();
    if (t == 0) {
        float T = pr[0] + pr[1] + pr[2] + pr[3];
        int A = 0;
#pragma unroll
        for (int c = 0; c < NCLS; c++) A += (ncls[c] >= 1000u) ? 1 : 0;
        out[0] = (A > 0) ? T / (448.0f * (float)A) : 0.0f;
    }
}

// ---------------------------------------------------------------------------
// Workspace layout (16B-aligned where needed):
//   cnt   : NCLS*SRC              = 311,296 B  @ 0
//   minfo : NPAIR*16              =  19,456 B  @ 311,296   (16-aligned)
//   ncls  : NCLS*4 (pad 128)      =     128 B  @ 330,752
//   bins  : NPAIR*KSL*7*4         = 136,192 B  @ 330,880
// total 467,072 B
// ---------------------------------------------------------------------------
extern "C" void kernel_launch(void* const* d_in, const int* in_sizes, int n_in,
                              void* d_out, int out_size, void* d_ws, size_t ws_size,
                              hipStream_t stream)
{
    const float* feature = (const float*)d_in[0];   // [1,64,128,128] fp32
    const int*   label   = (const int*)d_in[1];     // [1,1,512,512]  int32
    float*       out     = (float*)d_out;           // scalar fp32

    char* ws = (char*)d_ws;
    unsigned char* cnt   = (unsigned char*)(ws);
    float4*        minfo = (float4*)(ws + 311296);
    unsigned int*  ncls  = (unsigned int*)(ws + 330752);
    float*         bins  = (float*)(ws + 330880);

    hl_count_kernel<<<SRC / 256, 256, 0, stream>>>(label, cnt);
    hl_moments<<<NPAIR, 256, 0, stream>>>(feature, cnt, minfo, ncls);
    hl_kde<<<NPAIR * KSL, 256, 0, stream>>>(feature, cnt, minfo, bins);
    hl_final_kernel<<<1, 256, 0, stream>>>(bins, ncls, out);
}